// Round 5
// baseline (608.128 us; speedup 1.0000x reference)
//
#include <hip/hip_runtime.h>

#define ND 5000
#define NN 20000
#define FEA 256
#define EPOS 250000
#define MROW 500000
#define OUT_HALF 1000000

typedef unsigned int uint;
typedef unsigned short ushort;
typedef short bf16x8 __attribute__((ext_vector_type(8)));
typedef float f32x4 __attribute__((ext_vector_type(4)));

__device__ __forceinline__ ushort f2bf(float f) {
  union { float f; uint u; } c; c.f = f;
  uint u = c.u;
  u = (u + 0x7fffu + ((u >> 16) & 1u)) >> 16;  // RNE; inputs finite
  return (ushort)u;
}
__device__ __forceinline__ float bf2f(ushort h) {
  union { uint u; float f; } c; c.u = ((uint)h) << 16; return c.f;
}
// split v ~= hi + lo with hi,lo bf16 (residual ~2^-17 relative)
__device__ __forceinline__ void split2(float v, ushort& hi, ushort& lo) {
  hi = f2bf(v);
  lo = f2bf(v - bf2f(hi));
}
__device__ __forceinline__ void pk2s(float a, float b, uint& wh, uint& wl) {
  ushort ah, al, bh, bl;
  split2(a, ah, al); split2(b, bh, bl);
  wh = (uint)ah | ((uint)bh << 16);
  wl = (uint)al | ((uint)bl << 16);
}

// Transpose weight [K][N] fp32 -> [N][K] bf16 hi+lo
__global__ __launch_bounds__(256) void k_tx(const float* __restrict__ W, ushort* __restrict__ WTh,
                                            ushort* __restrict__ WTl, int K, int N) {
  int t = blockIdx.x * 256 + threadIdx.x;
  if (t >= K * N) return;
  int c = t / K, k = t - c * K;
  ushort hi, lo;
  split2(W[(size_t)k * N + c], hi, lo);
  WTh[t] = hi; WTl[t] = lo;
}

__global__ __launch_bounds__(256) void k_deg(const int* __restrict__ pos, const int* __restrict__ neg,
                                             int* __restrict__ deg) {
  int i = blockIdx.x * 256 + threadIdx.x;
  if (i >= MROW) return;
  int d = (i < EPOS) ? pos[EPOS + i] : neg[i];  // neg[EPOS + (i-EPOS)]
  atomicAdd(&deg[d], 1);
}

__global__ __launch_bounds__(1024) void k_scan(const int* __restrict__ deg, int* __restrict__ off) {
  __shared__ int buf[1024];
  __shared__ int sbase;
  if (threadIdx.x == 0) sbase = 0;
  __syncthreads();
  for (int start = 0; start < NN; start += 1024) {
    int i = start + threadIdx.x;
    int v = (i < NN) ? deg[i] : 0;
    buf[threadIdx.x] = v;
    __syncthreads();
    for (int s = 1; s < 1024; s <<= 1) {
      int t = (threadIdx.x >= s) ? buf[threadIdx.x - s] : 0;
      __syncthreads();
      buf[threadIdx.x] += t;
      __syncthreads();
    }
    int incl = buf[threadIdx.x];
    if (i < NN) off[i] = sbase + incl - v;  // exclusive
    __syncthreads();
    if (threadIdx.x == 1023) sbase += buf[1023];
    __syncthreads();
  }
}

__global__ __launch_bounds__(256) void k_scatter(const int* __restrict__ pos, const int* __restrict__ neg,
                                                 const int* __restrict__ off, int* __restrict__ cur,
                                                 int* __restrict__ ecol) {
  int i = blockIdx.x * 256 + threadIdx.x;
  if (i >= MROW) return;
  int s, d;
  if (i < EPOS) { s = pos[i]; d = pos[EPOS + i]; }
  else          { s = neg[i - EPOS]; d = neg[i]; }
  int p = atomicAdd(&cur[d], 1);
  ecol[off[d] + p] = s;
}

// mean_h[j][0:128] = (sum over incoming edges of z[src]) / max(deg,1); one wave per j
__global__ __launch_bounds__(256) void k_mean(const float* __restrict__ z, const int* __restrict__ off,
                                              const int* __restrict__ deg, const int* __restrict__ ecol,
                                              float* __restrict__ mh) {
  int j = blockIdx.x * 4 + (threadIdx.x >> 6);
  if (j >= NN) return;
  int lane = threadIdx.x & 63;
  int st = off[j], c = deg[j];
  float a0 = 0.f, a1 = 0.f;
  for (int e = 0; e < c; ++e) {
    int k = ecol[st + e];
    a0 += z[(size_t)k * 128 + lane];
    a1 += z[(size_t)k * 128 + 64 + lane];
  }
  float inv = 1.0f / (float)(c > 0 ? c : 1);
  mh[(size_t)j * 128 + lane]      = a0 * inv;
  mh[(size_t)j * 128 + 64 + lane] = a1 * inv;
}

#define MFMA3(ah, al, bh, bl, acc) \
  acc = __builtin_amdgcn_mfma_f32_16x16x32_bf16(al, bh, acc, 0, 0, 0); \
  acc = __builtin_amdgcn_mfma_f32_16x16x32_bf16(ah, bl, acc, 0, 0, 0); \
  acc = __builtin_amdgcn_mfma_f32_16x16x32_bf16(ah, bh, acc, 0, 0, 0);

// MODE 0: z = (n_fea[s]*n_fea[d]) @ Wl for rows < NN   (fp32 z out)
// MODE 1: full fused row pipeline -> log_softmax + label
// 64 rows/block, 256 threads (4 waves). All GEMMs are split-bf16 (hi/lo) emulated-fp32.
// LDS (64KB): X_hi ushort[0,16384), X_lo [16384,32768);
//   after GEMM1: h_hi [0,8192), h_lo [8192,16384), o1_hi [16384,20480), o1_lo [20480,24576)
template <int MODE>
__global__ __launch_bounds__(256) void k_rows(
    const float* __restrict__ drug, const float* __restrict__ prot,
    const int* __restrict__ pos, const int* __restrict__ neg,
    const ushort* __restrict__ WTh, const ushort* __restrict__ WTl,    // [128][256]
    const float* __restrict__ bl,
    const ushort* __restrict__ W1Th, const ushort* __restrict__ W1Tl,  // [64][128]
    const float* __restrict__ b1,
    const ushort* __restrict__ W2Th, const ushort* __restrict__ W2Tl,  // [32][64]
    const float* __restrict__ b2,
    const float* __restrict__ W3,    // [32][2] fp32
    const float* __restrict__ b3,
    const float* __restrict__ mh,    // [NN][128] fp32
    float* __restrict__ zout, float* __restrict__ out) {
  __shared__ uint4 xbuf4[4096];              // 64 KB
  ushort* xbuf = (ushort*)xbuf4;
  const int tid = threadIdx.x;
  const int base = blockIdx.x * 64;

  // ---- stage X tile: 4 threads per row, 64 k each; write hi+lo tiles ----
  {
    const int r = tid >> 2, q = tid & 3;
    int gi = base + r;
    if (gi > MROW - 1) gi = MROW - 1;
    int s, d;
    if (gi < EPOS) { s = pos[gi]; d = pos[EPOS + gi]; }
    else           { s = neg[gi - EPOS]; d = neg[gi]; }
    const float* pa = (s < ND) ? (drug + (size_t)s * FEA) : (prot + (size_t)(s - ND) * FEA);
    const float* pb = (d < ND) ? (drug + (size_t)d * FEA) : (prot + (size_t)(d - ND) * FEA);
    const float4* pa4 = (const float4*)(pa + q * 64);
    const float4* pb4 = (const float4*)(pb + q * 64);
#pragma unroll
    for (int it = 0; it < 8; ++it) {
      float4 a0 = pa4[it * 2], a1 = pa4[it * 2 + 1];
      float4 c0 = pb4[it * 2], c1 = pb4[it * 2 + 1];
      uint h0, l0, h1, l1, h2, l2, h3, l3;
      pk2s(a0.x * c0.x, a0.y * c0.y, h0, l0);
      pk2s(a0.z * c0.z, a0.w * c0.w, h1, l1);
      pk2s(a1.x * c1.x, a1.y * c1.y, h2, l2);
      pk2s(a1.z * c1.z, a1.w * c1.w, h3, l3);
      int slot = ((q << 3) + it) ^ (r & 7);
      xbuf4[(r << 5) + slot]        = make_uint4(h0, h1, h2, h3);
      xbuf4[2048 + (r << 5) + slot] = make_uint4(l0, l1, l2, l3);
    }
  }
  __syncthreads();

  const int lane = tid & 63, wv = tid >> 6;
  const int l15 = lane & 15, lg = lane >> 4;

  // ---- GEMM1: X[64x256] @ W[256x128], split hi/lo ----
  f32x4 acc[4][2] = {};
  const int col0 = (wv << 5) + l15;
  const int col1 = col0 + 16;
#pragma unroll
  for (int kk = 0; kk < 8; ++kk) {
    const int boff0 = (col0 << 8) + (kk << 5) + (lg << 3);
    const int boff1 = (col1 << 8) + (kk << 5) + (lg << 3);
    bf16x8 b0h = *(const bf16x8*)(WTh + boff0);
    bf16x8 b0l = *(const bf16x8*)(WTl + boff0);
    bf16x8 b1h = *(const bf16x8*)(WTh + boff1);
    bf16x8 b1l = *(const bf16x8*)(WTl + boff1);
#pragma unroll
    for (int m = 0; m < 4; ++m) {
      int row = (m << 4) + l15;
      int aoff = (row << 8) + ((((kk << 2) + lg) ^ (row & 7)) << 3);
      bf16x8 ah = *(const bf16x8*)(xbuf + aoff);
      bf16x8 al = *(const bf16x8*)(xbuf + 16384 + aoff);
      MFMA3(ah, al, b0h, b0l, acc[m][0]);
      MFMA3(ah, al, b1h, b1l, acc[m][1]);
    }
  }

  if (MODE == 0) {
    // D layout: col = lane&15 (+16n), row = (lane>>4)*4 + j (+16m)
#pragma unroll
    for (int m = 0; m < 4; ++m)
#pragma unroll
      for (int j = 0; j < 4; ++j) {
        int gi = base + (m << 4) + (lg << 2) + j;
        if (gi < NN) {
          zout[(size_t)gi * 128 + col0] = acc[m][0][j];
          zout[(size_t)gi * 128 + col1] = acc[m][1][j];
        }
      }
    return;
  }

  // ---- epilogue 1: + bl + mean_h (rows < NN), relu, write split h to LDS ----
  __syncthreads();  // all waves done reading X before overwrite
  {
    float blv0 = bl[col0], blv1 = bl[col1];
    bool hm = (base < NN);
#pragma unroll
    for (int m = 0; m < 4; ++m)
#pragma unroll
      for (int j = 0; j < 4; ++j) {
        int lr = (m << 4) + (lg << 2) + j;
        int gi = base + lr;
        float v0 = acc[m][0][j] + blv0;
        float v1 = acc[m][1][j] + blv1;
        if (hm && gi < NN) {
          v0 += mh[(size_t)gi * 128 + col0];
          v1 += mh[(size_t)gi * 128 + col1];
        }
        v0 = fmaxf(v0, 0.0f);
        v1 = fmaxf(v1, 0.0f);
        int sw = lr & 7;
        int hx0 = (lr << 7) + ((((col0 >> 3) ^ sw) << 3) | (col0 & 7));
        int hx1 = (lr << 7) + ((((col1 >> 3) ^ sw) << 3) | (col1 & 7));
        ushort hh, hl;
        split2(v0, hh, hl);
        xbuf[hx0] = hh; xbuf[8192 + hx0] = hl;
        split2(v1, hh, hl);
        xbuf[hx1] = hh; xbuf[8192 + hx1] = hl;
      }
  }
  __syncthreads();

  // ---- GEMM2: h[64x128] @ W1[128x64], split ----
  f32x4 acc2[4] = {};
  const int c2 = (wv << 4) + l15;
#pragma unroll
  for (int kk = 0; kk < 4; ++kk) {
    const int boff = (c2 << 7) + (kk << 5) + (lg << 3);
    bf16x8 bh = *(const bf16x8*)(W1Th + boff);
    bf16x8 bl_ = *(const bf16x8*)(W1Tl + boff);
#pragma unroll
    for (int m = 0; m < 4; ++m) {
      int row = (m << 4) + l15;
      int aoff = (row << 7) + ((((kk << 2) + lg) ^ (row & 7)) << 3);
      bf16x8 ah = *(const bf16x8*)(xbuf + aoff);
      bf16x8 al = *(const bf16x8*)(xbuf + 8192 + aoff);
      MFMA3(ah, al, bh, bl_, acc2[m]);
    }
  }
  // epilogue 2 -> split o1 at ushort 16384 (hi) / 20480 (lo); disjoint from h
  {
    float b1v = b1[c2];
#pragma unroll
    for (int m = 0; m < 4; ++m)
#pragma unroll
      for (int j = 0; j < 4; ++j) {
        int lr = (m << 4) + (lg << 2) + j;
        float v = fmaxf(acc2[m][j] + b1v, 0.0f);
        int ox = (lr << 6) + ((((c2 >> 3) ^ (lr & 7)) << 3) | (c2 & 7));
        ushort oh, ol;
        split2(v, oh, ol);
        xbuf[16384 + ox] = oh; xbuf[20480 + ox] = ol;
      }
  }
  __syncthreads();

  // ---- GEMM3: o1[64x64] @ W2[64x32], split; wave wv owns rows 16wv..16wv+15 ----
  f32x4 acc3[2] = {};
#pragma unroll
  for (int kk = 0; kk < 2; ++kk) {
    int row = (wv << 4) + l15;
    int aoff = (row << 6) + ((((kk << 2) + lg) ^ (row & 7)) << 3);
    bf16x8 ah = *(const bf16x8*)(xbuf + 16384 + aoff);
    bf16x8 al = *(const bf16x8*)(xbuf + 20480 + aoff);
    const int b0off = (l15 << 6) + (kk << 5) + (lg << 3);
    const int b1off = ((l15 + 16) << 6) + (kk << 5) + (lg << 3);
    bf16x8 bb0h = *(const bf16x8*)(W2Th + b0off);
    bf16x8 bb0l = *(const bf16x8*)(W2Tl + b0off);
    bf16x8 bb1h = *(const bf16x8*)(W2Th + b1off);
    bf16x8 bb1l = *(const bf16x8*)(W2Tl + b1off);
    MFMA3(ah, al, bb0h, bb0l, acc3[0]);
    MFMA3(ah, al, bb1h, bb1l, acc3[1]);
  }
  // ---- layer4 (32 -> 2) fp32 + log_softmax + label ----
  float b2v0 = b2[l15], b2v1 = b2[l15 + 16];
  float2 w30 = ((const float2*)W3)[l15];
  float2 w31 = ((const float2*)W3)[l15 + 16];
#pragma unroll
  for (int j = 0; j < 4; ++j) {
    float v0 = fmaxf(acc3[0][j] + b2v0, 0.0f);
    float v1 = fmaxf(acc3[1][j] + b2v1, 0.0f);
    float p0 = v0 * w30.x + v1 * w31.x;
    float p1 = v0 * w30.y + v1 * w31.y;
#pragma unroll
    for (int mk = 1; mk < 16; mk <<= 1) {
      p0 += __shfl_xor(p0, mk);
      p1 += __shfl_xor(p1, mk);
    }
    if (l15 == 0) {
      int gi = base + (wv << 4) + (lg << 2) + j;
      if (gi < MROW) {
        p0 += b3[0];
        p1 += b3[1];
        float mx = fmaxf(p0, p1);
        float lse = mx + logf(expf(p0 - mx) + expf(p1 - mx));
        out[(size_t)gi * 2]     = p0 - lse;
        out[(size_t)gi * 2 + 1] = p1 - lse;
        float lb = (gi < EPOS) ? 1.0f : 0.0f;
        out[OUT_HALF + (size_t)gi * 2]     = lb;
        out[OUT_HALF + (size_t)gi * 2 + 1] = lb;
      }
    }
  }
}

extern "C" void kernel_launch(void* const* d_in, const int* in_sizes, int n_in,
                              void* d_out, int out_size, void* d_ws, size_t ws_size,
                              hipStream_t stream) {
  const float* drug = (const float*)d_in[0];
  const float* prot = (const float*)d_in[1];
  const float* Wl = (const float*)d_in[2];
  const float* bl = (const float*)d_in[3];
  const float* Wr = (const float*)d_in[4];
  const float* W1 = (const float*)d_in[5];
  const float* b1 = (const float*)d_in[6];
  const float* W2 = (const float*)d_in[7];
  const float* b2 = (const float*)d_in[8];
  const float* W3 = (const float*)d_in[9];
  const float* b3 = (const float*)d_in[10];
  const int* pos = (const int*)d_in[11];
  const int* neg = (const int*)d_in[12];
  float* out = (float*)d_out;

  char* ws = (char*)d_ws;
  ushort* WrTh = (ushort*)(ws + 0);        // 64 KB each
  ushort* WrTl = (ushort*)(ws + 65536);
  ushort* WlTh = (ushort*)(ws + 131072);
  ushort* WlTl = (ushort*)(ws + 196608);
  ushort* W1Th = (ushort*)(ws + 262144);   // 16 KB each
  ushort* W1Tl = (ushort*)(ws + 278528);
  ushort* W2Th = (ushort*)(ws + 294912);   // 4 KB each
  ushort* W2Tl = (ushort*)(ws + 299008);
  float* z    = (float*)(ws + 303104);     // 10.24 MB
  float* mh   = (float*)(ws + 303104 + 10240000);   // 10.24 MB
  int* deg  = (int*)(ws + 20783104);       // 80 KB
  int* cur  = (int*)(ws + 20863104);       // 80 KB (contiguous with deg)
  int* off  = (int*)(ws + 20943104);       // 80 KB
  int* ecol = (int*)(ws + 21023104);       // 2 MB

  // weight transposes -> split bf16
  k_tx<<<128, 256, 0, stream>>>(Wr, WrTh, WrTl, 256, 128);
  k_tx<<<128, 256, 0, stream>>>(Wl, WlTh, WlTl, 256, 128);
  k_tx<<<32, 256, 0, stream>>>(W1, W1Th, W1Tl, 128, 64);
  k_tx<<<8, 256, 0, stream>>>(W2, W2Th, W2Tl, 64, 32);

  hipMemsetAsync(deg, 0, 160000, stream);  // deg + cur

  // z = x[0:20000] @ Wl (split-precision)
  k_rows<0><<<313, 256, 0, stream>>>(drug, prot, pos, neg, WlTh, WlTl, nullptr,
                                     nullptr, nullptr, nullptr, nullptr, nullptr, nullptr,
                                     nullptr, nullptr, nullptr, z, nullptr);
  // CSR by dst + segmented mean
  k_deg<<<1954, 256, 0, stream>>>(pos, neg, deg);
  k_scan<<<1, 1024, 0, stream>>>(deg, off);
  k_scatter<<<1954, 256, 0, stream>>>(pos, neg, off, cur, ecol);
  k_mean<<<5000, 256, 0, stream>>>(z, off, deg, ecol, mh);

  // fused main pipeline
  k_rows<1><<<7813, 256, 0, stream>>>(drug, prot, pos, neg, WrTh, WrTl, bl,
                                      W1Th, W1Tl, b1, W2Th, W2Tl, b2, W3, b3,
                                      mh, nullptr, out);
}